// Round 5
// baseline (183.074 us; speedup 1.0000x reference)
//
#include <hip/hip_runtime.h>
#include <math.h>

// VP-SDE Euler-Maruyama forward diffusion (fp32).
// out[0] = x; out[t+1] = a_t * out[t] + b_t * noise[t],  t = 0..99
// beta_t = 0.1 + (t/100)*19.9; a_t = 1 - 0.5*beta_t/100; b_t = sqrt(beta_t)/10.
//
// ~808 MB irreducible traffic -> ~128 us floor @6.3 TB/s.
// R1: 199.8 us (naive unroll4). R4: 178.5 us (ping-pong prefetch + nt ld/st).
// R5 theory: in-order vmcnt makes each window wait on the PREVIOUS window's
// stores; nt stores ack at HBM (~900cy) -> critical path. Fix: plain cached
// stores (ack at L2, write-back drains async - the 6.9 TB/s fill path),
// nt loads only (keep L2 free for store buffering), launch_bounds(256,4)
// to guarantee 4 blocks/CU co-residency.

#define S_STEPS 100
#define U 5                    // timesteps per window
#define NW (S_STEPS / U)       // 20 windows (even -> clean ping-pong)

typedef float f32x4 __attribute__((ext_vector_type(4)));

__global__ __launch_bounds__(256, 4) void vpsde_fwd_kernel(
    const f32x4* __restrict__ x,
    const f32x4* __restrict__ noise,
    f32x4* __restrict__ out,
    int ne4)  // float4 elements per timestep
{
    __shared__ float s_a[S_STEPS];
    __shared__ float s_b[S_STEPS];

    const int tid = threadIdx.x;
    if (tid < S_STEPS) {
        const float dt = 0.01f;
        float nt_ = (float)tid * dt;          // (t-1)/S for t=1..S
        float beta = 0.1f + nt_ * 19.9f;
        s_a[tid] = 1.0f - 0.5f * beta * dt;
        s_b[tid] = sqrtf(beta) * 0.1f;        // sqrt(beta)*sqrt(dt)
    }
    __syncthreads();

    const int idx = blockIdx.x * blockDim.x + tid;
    if (idx >= ne4) return;

    f32x4 xv = x[idx];
    out[idx] = xv;                            // out[0] = x (plain store)

    // Running pointers, bumped once per window (U timesteps each).
    const f32x4* nload = noise + idx;         // next window to prefetch from
    const f32x4* ncons;                       // (offsets applied per window)
    f32x4* ostore = out + idx + (size_t)ne4;  // out[t+1] for t = window base

    f32x4 A[U], B[U];

    auto loadw = [&](f32x4* buf, const f32x4* base) {
        #pragma unroll
        for (int k = 0; k < U; ++k)
            buf[k] = __builtin_nontemporal_load(base + (size_t)k * ne4);
    };
    auto consume = [&](const f32x4* buf, int t0, f32x4* obase) {
        #pragma unroll
        for (int k = 0; k < U; ++k) {
            const float a = s_a[t0 + k];
            const float b = s_b[t0 + k];
            xv = a * xv + b * buf[k];          // componentwise fma
            obase[(size_t)k * ne4] = xv;       // plain cached store
        }
    };

    // Ping-pong software pipeline: window w+1's loads are in flight while
    // window w is consumed.
    loadw(A, nload);  nload += (size_t)U * ne4;
    for (int w = 0; w < NW; w += 2) {
        loadw(B, nload);  nload += (size_t)U * ne4;        // prefetch w+1
        consume(A, w * U, ostore);  ostore += (size_t)U * ne4;
        if (w + 2 < NW) { loadw(A, nload);  nload += (size_t)U * ne4; }
        consume(B, (w + 1) * U, ostore);  ostore += (size_t)U * ne4;
    }
}

extern "C" void kernel_launch(void* const* d_in, const int* in_sizes, int n_in,
                              void* d_out, int out_size, void* d_ws, size_t ws_size,
                              hipStream_t stream) {
    const float* x     = (const float*)d_in[0];   // (64,256,64)
    const float* noise = (const float*)d_in[1];   // (100,64,256,64)
    float* out         = (float*)d_out;           // (101,64,256,64)

    const int ne  = in_sizes[0];       // 1,048,576 elements per timestep
    const int ne4 = ne / 4;            // 262,144 float4 per timestep

    const int block = 256;
    const int grid  = (ne4 + block - 1) / block;  // 1024 blocks (4/CU)

    vpsde_fwd_kernel<<<grid, block, 0, stream>>>(
        (const f32x4*)x, (const f32x4*)noise, (f32x4*)out, ne4);
}